// Round 1
// baseline (567.767 us; speedup 1.0000x reference)
//
#include <hip/hip_runtime.h>

// GCN forward: 2x GCNConv(64->64) + MLP(64->128->10), fp32.
// Inputs: x[ N,64 ], edge_index[2,E], edge_attr[E], W1[64,64], b1[64],
//         W2[64,64], b2[64], fc1_w[64,128], fc1_b[128], fc2_w[128,10], fc2_b[10]

#define NFEAT 64

__global__ void k_fill1(float* __restrict__ p, int n) {
    int i = blockIdx.x * blockDim.x + threadIdx.x;
    if (i < n) p[i] = 1.0f;
}

__global__ void k_degcount(const int* __restrict__ row, float* __restrict__ deg, int ne) {
    int i = blockIdx.x * blockDim.x + threadIdx.x;
    int st = gridDim.x * blockDim.x;
    for (; i < ne; i += st) atomicAdd(&deg[row[i]], 1.0f);
}

__global__ void k_rsqrt(float* __restrict__ p, int n) {
    int i = blockIdx.x * blockDim.x + threadIdx.x;
    if (i < n) p[i] = rsqrtf(p[i]);
}

__global__ void k_norm(const int* __restrict__ row, const int* __restrict__ col,
                       const float* __restrict__ ew, const float* __restrict__ dis,
                       float* __restrict__ nw, int ne) {
    int i = blockIdx.x * blockDim.x + threadIdx.x;
    int st = gridDim.x * blockDim.x;
    for (; i < ne; i += st) nw[i] = dis[row[i]] * ew[i] * dis[col[i]];
}

// Y[nrows,64] = op(X)[nrows,64] @ W[64,64]; op = relu(x + bias_in) if RELU_BIAS
template <bool RELU_BIAS>
__global__ __launch_bounds__(256) void k_gemm64(const float* __restrict__ X,
                                                const float* __restrict__ W,
                                                const float* __restrict__ bias_in,
                                                float* __restrict__ Y, int nrows) {
    __shared__ float Wl[64 * 64];
    __shared__ float Xl[32 * 64];
    int tid = threadIdx.x;
    for (int i = tid; i < 64 * 64; i += 256) Wl[i] = W[i];
    int r0 = blockIdx.x * 32;
    for (int i = tid; i < 32 * 64; i += 256) {
        int rr = r0 + (i >> 6);
        float v = 0.f;
        if (rr < nrows) {
            v = X[r0 * 64 + i];
            if (RELU_BIAS) v = fmaxf(v + bias_in[i & 63], 0.f);
        }
        Xl[i] = v;
    }
    __syncthreads();
    int f = tid & 63;
    int rbase = tid >> 6;  // 0..3 (uniform per wave)
    float acc[8];
#pragma unroll
    for (int j = 0; j < 8; ++j) acc[j] = 0.f;
#pragma unroll 4
    for (int k = 0; k < 64; ++k) {
        float w = Wl[k * 64 + f];
#pragma unroll
        for (int j = 0; j < 8; ++j) acc[j] += Xl[(rbase + j * 4) * 64 + k] * w;
    }
#pragma unroll
    for (int j = 0; j < 8; ++j) {
        int rr = r0 + rbase + j * 4;
        if (rr < nrows) Y[rr * 64 + f] = acc[j];
    }
}

// AGG[i][f] = dis[i]^2 * H[i][f]   (self-loop contribution; also zero-init)
__global__ void k_selfinit(const float* __restrict__ dis, const float* __restrict__ H,
                           float* __restrict__ AGG, int total) {
    int idx = blockIdx.x * blockDim.x + threadIdx.x;
    int st = gridDim.x * blockDim.x;
    int n4 = total >> 2;
    for (; idx < n4; idx += st) {
        int node = (idx << 2) >> 6;
        float d = dis[node];
        float s = d * d;
        float4 h = ((const float4*)H)[idx];
        float4 o = make_float4(s * h.x, s * h.y, s * h.z, s * h.w);
        ((float4*)AGG)[idx] = o;
    }
}

// AGG[row[e]][:] += nw[e] * H[col[e]][:]   one wave per edge, lane = feature
__global__ __launch_bounds__(256) void k_scatter(const int* __restrict__ row,
                                                 const int* __restrict__ col,
                                                 const float* __restrict__ nw,
                                                 const float* __restrict__ H,
                                                 float* __restrict__ AGG, int ne) {
    int lane = threadIdx.x & 63;
    int wid = (blockIdx.x * blockDim.x + threadIdx.x) >> 6;
    int nwaves = (gridDim.x * blockDim.x) >> 6;
    for (int e = wid; e < ne; e += nwaves) {
        int r = row[e];
        int c = col[e];
        float w = nw[e];
        float v = w * H[c * 64 + lane];
        atomicAdd(&AGG[r * 64 + lane], v);
    }
}

// out[i,:] = relu((AGG[i,:]+b2) @ fc1_w + fc1_b) @ fc2_w + fc2_b
__global__ __launch_bounds__(256) void k_mlp(const float* __restrict__ AGG,
                                             const float* __restrict__ b2,
                                             const float* __restrict__ fc1w,
                                             const float* __restrict__ fc1b,
                                             const float* __restrict__ fc2w,
                                             const float* __restrict__ fc2b,
                                             float* __restrict__ out, int n) {
    __shared__ float W1l[64 * 128];
    __shared__ float W2l[128 * 10];
    __shared__ float b1l[128];
    __shared__ float b2l[16];
    __shared__ float binl[64];
    int tid = threadIdx.x;
    for (int i = tid; i < 64 * 128; i += 256) W1l[i] = fc1w[i];
    for (int i = tid; i < 128 * 10; i += 256) W2l[i] = fc2w[i];
    if (tid < 128) b1l[tid] = fc1b[tid];
    if (tid < 10) b2l[tid] = fc2b[tid];
    if (tid < 64) binl[tid] = b2[tid];
    __syncthreads();
    int i = blockIdx.x * blockDim.x + tid;
    int st = gridDim.x * blockDim.x;
    for (; i < n; i += st) {
        float v[64];
#pragma unroll
        for (int k4 = 0; k4 < 16; ++k4) {
            float4 h = ((const float4*)(AGG + (size_t)i * 64))[k4];
            v[k4 * 4 + 0] = h.x + binl[k4 * 4 + 0];
            v[k4 * 4 + 1] = h.y + binl[k4 * 4 + 1];
            v[k4 * 4 + 2] = h.z + binl[k4 * 4 + 2];
            v[k4 * 4 + 3] = h.w + binl[k4 * 4 + 3];
        }
        float acc[10];
#pragma unroll
        for (int c = 0; c < 10; ++c) acc[c] = b2l[c];
        for (int j = 0; j < 128; j += 4) {
            float4 h4 = make_float4(b1l[j], b1l[j + 1], b1l[j + 2], b1l[j + 3]);
#pragma unroll
            for (int k = 0; k < 64; ++k) {
                float4 w = *(const float4*)&W1l[k * 128 + j];
                h4.x += v[k] * w.x;
                h4.y += v[k] * w.y;
                h4.z += v[k] * w.z;
                h4.w += v[k] * w.w;
            }
            h4.x = fmaxf(h4.x, 0.f);
            h4.y = fmaxf(h4.y, 0.f);
            h4.z = fmaxf(h4.z, 0.f);
            h4.w = fmaxf(h4.w, 0.f);
#pragma unroll
            for (int c = 0; c < 10; ++c) {
                acc[c] += h4.x * W2l[(j + 0) * 10 + c];
                acc[c] += h4.y * W2l[(j + 1) * 10 + c];
                acc[c] += h4.z * W2l[(j + 2) * 10 + c];
                acc[c] += h4.w * W2l[(j + 3) * 10 + c];
            }
        }
#pragma unroll
        for (int c = 0; c < 10; ++c) out[(size_t)i * 10 + c] = acc[c];
    }
}

extern "C" void kernel_launch(void* const* d_in, const int* in_sizes, int n_in,
                              void* d_out, int out_size, void* d_ws, size_t ws_size,
                              hipStream_t stream) {
    const float* x        = (const float*)d_in[0];
    const int*   eidx     = (const int*)d_in[1];
    const float* eattr    = (const float*)d_in[2];
    const float* W1       = (const float*)d_in[3];
    const float* b1       = (const float*)d_in[4];
    const float* W2       = (const float*)d_in[5];
    const float* b2       = (const float*)d_in[6];
    const float* fc1w     = (const float*)d_in[7];
    const float* fc1b     = (const float*)d_in[8];
    const float* fc2w     = (const float*)d_in[9];
    const float* fc2b     = (const float*)d_in[10];
    float* out = (float*)d_out;

    const int N = in_sizes[0] / NFEAT;   // 50000
    const int E = in_sizes[2];           // 800000
    const int* row = eidx;
    const int* col = eidx + E;

    // workspace layout (floats), 16B-aligned sections
    float* wsf  = (float*)d_ws;
    float* deg  = wsf;                    // N       (becomes dis = deg^-1/2)
    float* nw   = wsf + 50176;            // E       edge norm weights
    float* bufA = nw + 800000;            // N*64    H (XW) buffer
    float* bufB = bufA + 3200000;         // N*64    AGG buffer

    const int TB = 256;
    int gN   = (N + TB - 1) / TB;         // 196
    int gE   = (E + TB - 1) / TB;         // 3125
    int gG   = (N + 31) / 32;             // 1563 gemm blocks
    int gEl  = (N * NFEAT / 4 + TB - 1) / TB;

    // 1) degrees (self-loop => init 1)
    k_fill1<<<gN, TB, 0, stream>>>(deg, N);
    k_degcount<<<gE, TB, 0, stream>>>(row, deg, E);
    k_rsqrt<<<gN, TB, 0, stream>>>(deg, N);
    // 2) edge norm weights
    k_norm<<<gE, TB, 0, stream>>>(row, col, eattr, deg, nw, E);

    // ---- layer 1 ----
    k_gemm64<false><<<gG, TB, 0, stream>>>(x, W1, nullptr, bufA, N);
    k_selfinit<<<gEl, TB, 0, stream>>>(deg, bufA, bufB, N * NFEAT);
    k_scatter<<<4096, TB, 0, stream>>>(row, col, nw, bufA, bufB, E);

    // ---- layer 2 ---- (input transform: relu(agg1 + b1))
    k_gemm64<true><<<gG, TB, 0, stream>>>(bufB, W2, b1, bufA, N);
    k_selfinit<<<gEl, TB, 0, stream>>>(deg, bufA, bufB, N * NFEAT);
    k_scatter<<<4096, TB, 0, stream>>>(row, col, nw, bufA, bufB, E);

    // ---- MLP head ---- (adds b2, no relu on conv2 output)
    k_mlp<<<gN, TB, 0, stream>>>(bufB, b2, fc1w, fc1b, fc2w, fc2b, out, N);
}

// Round 2
// 354.002 us; speedup vs baseline: 1.6039x; 1.6039x over previous
//
#include <hip/hip_runtime.h>

// GCN forward: 2x GCNConv(64->64) + MLP(64->128->10), fp32, pull-based CSR.
// Inputs: x[N,64], edge_index[2,E], edge_attr[E], W1[64,64], b1[64],
//         W2[64,64], b2[64], fc1_w[64,128], fc1_b[128], fc2_w[128,10], fc2_b[10]

#define NFEAT 64

// ---- CSR build ----------------------------------------------------------

__global__ void k_hist(const int* __restrict__ row, int* __restrict__ cnt, int ne) {
    int i = blockIdx.x * blockDim.x + threadIdx.x;
    int st = gridDim.x * blockDim.x;
    for (; i < ne; i += st) atomicAdd(&cnt[row[i]], 1);
}

__global__ void k_dis(const int* __restrict__ cnt, float* __restrict__ dis, int n) {
    int i = blockIdx.x * blockDim.x + threadIdx.x;
    if (i < n) dis[i] = rsqrtf(1.0f + (float)cnt[i]);
}

__global__ void k_scanA(const int* __restrict__ cnt, int* __restrict__ bsum, int n) {
    __shared__ int s[256];
    int tid = threadIdx.x;
    int i = blockIdx.x * 256 + tid;
    s[tid] = (i < n) ? cnt[i] : 0;
    __syncthreads();
    for (int d = 128; d > 0; d >>= 1) {
        if (tid < d) s[tid] += s[tid + d];
        __syncthreads();
    }
    if (tid == 0) bsum[blockIdx.x] = s[0];
}

__global__ void k_scanB(const int* __restrict__ bsum, int* __restrict__ bpre, int nb) {
    __shared__ int s[256];
    int tid = threadIdx.x;
    int v = (tid < nb) ? bsum[tid] : 0;
    s[tid] = v;
    __syncthreads();
    for (int d = 1; d < 256; d <<= 1) {
        int t = (tid >= d) ? s[tid - d] : 0;
        __syncthreads();
        s[tid] += t;
        __syncthreads();
    }
    if (tid < nb) bpre[tid] = s[tid] - v;  // exclusive
}

__global__ void k_scanC(const int* __restrict__ cnt, const int* __restrict__ bpre,
                        int* __restrict__ off, int n) {
    __shared__ int s[256];
    int tid = threadIdx.x;
    int i = blockIdx.x * 256 + tid;
    int v = (i < n) ? cnt[i] : 0;
    s[tid] = v;
    __syncthreads();
    for (int d = 1; d < 256; d <<= 1) {
        int t = (tid >= d) ? s[tid - d] : 0;
        __syncthreads();
        s[tid] += t;
        __syncthreads();
    }
    if (i < n) off[i] = bpre[blockIdx.x] + s[tid] - v;  // exclusive start
}

// slot = off[row]++ ; csr[slot] = {col, w}. After this, off[i] == segment END.
__global__ void k_fill(const int* __restrict__ row, const int* __restrict__ col,
                       const float* __restrict__ ew, const float* __restrict__ dis,
                       int* __restrict__ off, int2* __restrict__ csr, int ne) {
    int i = blockIdx.x * blockDim.x + threadIdx.x;
    int st = gridDim.x * blockDim.x;
    for (; i < ne; i += st) {
        int r = row[i], c = col[i];
        float w = dis[r] * ew[i] * dis[c];
        int slot = atomicAdd(&off[r], 1);
        csr[slot] = make_int2(c, __float_as_int(w));
    }
}

// ---- dense: Y[nrows,64] = op(X) @ W[64,64]; op = relu(x+bias) if RELU_BIAS --

template <bool RELU_BIAS>
__global__ __launch_bounds__(256) void k_gemm64(const float* __restrict__ X,
                                                const float* __restrict__ W,
                                                const float* __restrict__ bias_in,
                                                float* __restrict__ Y, int nrows) {
    __shared__ float Wl[64 * 64];   // [k][f]
    __shared__ float XT[64 * 68];   // [k][r], padded
    int tid = threadIdx.x;
    int r0 = blockIdx.x * 64;
    for (int i = tid; i < 64 * 64; i += 256) Wl[i] = W[i];
    for (int i = tid; i < 64 * 64; i += 256) {
        int r = i >> 6, k = i & 63;
        int rr = r0 + r;
        float v = 0.f;
        if (rr < nrows) {
            v = X[(size_t)r0 * 64 + i];
            if (RELU_BIAS) v = fmaxf(v + bias_in[k], 0.f);
        }
        XT[k * 68 + r] = v;
    }
    __syncthreads();
    int f4 = (tid & 15) * 4;
    int r4 = (tid >> 4) * 4;
    float acc[4][4];
#pragma unroll
    for (int i = 0; i < 4; ++i)
#pragma unroll
        for (int j = 0; j < 4; ++j) acc[i][j] = 0.f;
#pragma unroll 8
    for (int k = 0; k < 64; ++k) {
        float4 w = *(const float4*)&Wl[k * 64 + f4];
        float4 xv = *(const float4*)&XT[k * 68 + r4];
        float xs[4] = {xv.x, xv.y, xv.z, xv.w};
        float ws[4] = {w.x, w.y, w.z, w.w};
#pragma unroll
        for (int i = 0; i < 4; ++i)
#pragma unroll
            for (int j = 0; j < 4; ++j) acc[i][j] = fmaf(xs[i], ws[j], acc[i][j]);
    }
#pragma unroll
    for (int i = 0; i < 4; ++i) {
        int rr = r0 + r4 + i;
        if (rr < nrows) {
            float4 o = make_float4(acc[i][0], acc[i][1], acc[i][2], acc[i][3]);
            *(float4*)&Y[(size_t)rr * 64 + f4] = o;
        }
    }
}

// ---- pull aggregation: AGG[i] = dis[i]^2*H[i] + sum_in w*H[c] ------------

__global__ __launch_bounds__(256) void k_agg(const int* __restrict__ off_end,
                                             const int* __restrict__ cnt,
                                             const float* __restrict__ dis,
                                             const int2* __restrict__ csr,
                                             const float* __restrict__ H,
                                             float* __restrict__ AGG, int n) {
    int lane = threadIdx.x & 63;
    int node = (blockIdx.x * blockDim.x + threadIdx.x) >> 6;
    if (node >= n) return;
    int endv = off_end[node];
    int s = endv - cnt[node];
    float d = dis[node];
    float acc = d * d * H[(size_t)node * 64 + lane];
    for (; s + 2 <= endv; s += 2) {
        int2 p0 = csr[s];
        int2 p1 = csr[s + 1];
        float h0 = H[(size_t)p0.x * 64 + lane];
        float h1 = H[(size_t)p1.x * 64 + lane];
        acc = fmaf(__int_as_float(p0.y), h0, acc);
        acc = fmaf(__int_as_float(p1.y), h1, acc);
    }
    if (s < endv) {
        int2 p = csr[s];
        acc = fmaf(__int_as_float(p.y), H[(size_t)p.x * 64 + lane], acc);
    }
    AGG[(size_t)node * 64 + lane] = acc;
}

// ---- fused MLP head: out = relu((AGG+b2)@fc1 + fc1b) @ fc2 + fc2b --------

__global__ __launch_bounds__(256) void k_mlp(const float* __restrict__ AGG,
                                             const float* __restrict__ b2,
                                             const float* __restrict__ fc1w,
                                             const float* __restrict__ fc1b,
                                             const float* __restrict__ fc2w,
                                             const float* __restrict__ fc2b,
                                             float* __restrict__ out, int n) {
    __shared__ float W1l[64 * 128];   // [k][j]  32 KB
    __shared__ float buf[64 * 132];   // XT [k][r] (first 64*68) then Hl [r][j] padded 132
    __shared__ float W2l[128 * 10];
    __shared__ float b1l[128];
    __shared__ float b2c[16];
    __shared__ float binl[64];
    int tid = threadIdx.x;
    int r0 = blockIdx.x * 64;
    for (int i = tid; i < 64 * 128; i += 256) W1l[i] = fc1w[i];
    for (int i = tid; i < 128 * 10; i += 256) W2l[i] = fc2w[i];
    if (tid < 128) b1l[tid] = fc1b[tid];
    if (tid < 10) b2c[tid] = fc2b[tid];
    if (tid < 64) binl[tid] = b2[tid];
    __syncthreads();
    // stage input tile transposed: XT[k][r] = AGG[r0+r][k] + b2[k]
    for (int i = tid; i < 64 * 64; i += 256) {
        int r = i >> 6, k = i & 63;
        int rr = r0 + r;
        float v = 0.f;
        if (rr < n) v = AGG[(size_t)r0 * 64 + i] + binl[k];
        buf[k * 68 + r] = v;
    }
    __syncthreads();
    int f4 = (tid & 15) * 4;   // cols f4..f4+3 and 64+f4..64+f4+3
    int r4 = (tid >> 4) * 4;
    float acc[4][8];
#pragma unroll
    for (int i = 0; i < 4; ++i)
#pragma unroll
        for (int j = 0; j < 8; ++j) acc[i][j] = 0.f;
#pragma unroll 4
    for (int k = 0; k < 64; ++k) {
        float4 xv = *(const float4*)&buf[k * 68 + r4];
        float4 wa = *(const float4*)&W1l[k * 128 + f4];
        float4 wb = *(const float4*)&W1l[k * 128 + 64 + f4];
        float xs[4] = {xv.x, xv.y, xv.z, xv.w};
        float wl[8] = {wa.x, wa.y, wa.z, wa.w, wb.x, wb.y, wb.z, wb.w};
#pragma unroll
        for (int i = 0; i < 4; ++i)
#pragma unroll
            for (int j = 0; j < 8; ++j) acc[i][j] = fmaf(xs[i], wl[j], acc[i][j]);
    }
    __syncthreads();  // done reading XT; buf becomes Hl[r][j] (stride 132)
#pragma unroll
    for (int i = 0; i < 4; ++i) {
        int r = r4 + i;
#pragma unroll
        for (int j = 0; j < 4; ++j)
            buf[r * 132 + f4 + j] = fmaxf(acc[i][j] + b1l[f4 + j], 0.f);
#pragma unroll
        for (int j = 4; j < 8; ++j)
            buf[r * 132 + 64 + f4 + (j - 4)] = fmaxf(acc[i][j] + b1l[64 + f4 + (j - 4)], 0.f);
    }
    __syncthreads();
    // fc2: 64 rows x 10 cols; thread -> (r = tid>>2, 3 cols)
    int r = tid >> 2;
    int cg = tid & 3;
    float s0 = 0.f, s1 = 0.f, s2 = 0.f;
    int c0 = cg * 3, c1 = cg * 3 + 1, c2 = cg * 3 + 2;
    bool v1 = (c1 < 10), v2 = (c2 < 10);
#pragma unroll 8
    for (int j = 0; j < 128; ++j) {
        float hv = buf[r * 132 + j];
        s0 = fmaf(hv, W2l[j * 10 + c0], s0);
        if (v1) s1 = fmaf(hv, W2l[j * 10 + c1], s1);
        if (v2) s2 = fmaf(hv, W2l[j * 10 + c2], s2);
    }
    int rr = r0 + r;
    if (rr < n) {
        out[(size_t)rr * 10 + c0] = s0 + b2c[c0];
        if (v1) out[(size_t)rr * 10 + c1] = s1 + b2c[c1];
        if (v2) out[(size_t)rr * 10 + c2] = s2 + b2c[c2];
    }
}

// --------------------------------------------------------------------------

extern "C" void kernel_launch(void* const* d_in, const int* in_sizes, int n_in,
                              void* d_out, int out_size, void* d_ws, size_t ws_size,
                              hipStream_t stream) {
    const float* x     = (const float*)d_in[0];
    const int*   eidx  = (const int*)d_in[1];
    const float* eattr = (const float*)d_in[2];
    const float* W1    = (const float*)d_in[3];
    const float* b1    = (const float*)d_in[4];
    const float* W2    = (const float*)d_in[5];
    const float* b2    = (const float*)d_in[6];
    const float* fc1w  = (const float*)d_in[7];
    const float* fc1b  = (const float*)d_in[8];
    const float* fc2w  = (const float*)d_in[9];
    const float* fc2b  = (const float*)d_in[10];
    float* out = (float*)d_out;

    const int N = in_sizes[0] / NFEAT;   // 50000
    const int E = in_sizes[2];           // 800000
    const int* row = eidx;
    const int* col = eidx + E;

    // workspace layout
    int*   icnt = (int*)d_ws;                  // N (padded 50176)
    int*   off  = icnt + 50176;                // N
    float* dis  = (float*)(off + 50176);       // N
    int*   bsum = (int*)(dis + 50176);         // 256
    int*   bpre = bsum + 256;                  // 256
    int2*  csr  = (int2*)(bpre + 256);         // E  (8 B each, 8 B aligned)
    float* H    = (float*)(csr + E);           // N*64
    float* AGG  = H + (size_t)N * 64;          // N*64

    const int TB = 256;
    int gN = (N + TB - 1) / TB;                // 196
    int gG = (N + 63) / 64;                    // 782
    int gA = (N * 64 + TB - 1) / TB;           // 12500
    int nb = gN;                               // scan blocks

    hipMemsetAsync(icnt, 0, (size_t)N * sizeof(int), stream);
    k_hist<<<1024, TB, 0, stream>>>(row, icnt, E);
    k_dis<<<gN, TB, 0, stream>>>(icnt, dis, N);
    k_scanA<<<nb, TB, 0, stream>>>(icnt, bsum, N);
    k_scanB<<<1, TB, 0, stream>>>(bsum, bpre, nb);
    k_scanC<<<nb, TB, 0, stream>>>(icnt, bpre, off, N);
    k_fill<<<1024, TB, 0, stream>>>(row, col, eattr, dis, off, csr, E);

    // layer 1
    k_gemm64<false><<<gG, TB, 0, stream>>>(x, W1, nullptr, H, N);
    k_agg<<<gA, TB, 0, stream>>>(off, icnt, dis, csr, H, AGG, N);
    // layer 2
    k_gemm64<true><<<gG, TB, 0, stream>>>(AGG, W2, b1, H, N);
    k_agg<<<gA, TB, 0, stream>>>(off, icnt, dis, csr, H, AGG, N);
    // MLP head
    k_mlp<<<gG, TB, 0, stream>>>(AGG, b2, fc1w, fc1b, fc2w, fc2b, out, N);
}

// Round 3
// 302.449 us; speedup vs baseline: 1.8772x; 1.1705x over previous
//
#include <hip/hip_runtime.h>

// GCN forward: 2x GCNConv(64->64) + MLP(64->128->10), fp32, pull-based CSR.

#define NFEAT 64

// ---- CSR build ----------------------------------------------------------

__global__ void k_hist(const int* __restrict__ row, int* __restrict__ cnt, int ne) {
    int i = blockIdx.x * blockDim.x + threadIdx.x;
    int st = gridDim.x * blockDim.x;
    for (; i < ne; i += st) atomicAdd(&cnt[row[i]], 1);
}

__global__ void k_scanA(const int* __restrict__ cnt, int* __restrict__ bsum, int n) {
    __shared__ int s[256];
    int tid = threadIdx.x;
    int i = blockIdx.x * 256 + tid;
    s[tid] = (i < n) ? cnt[i] : 0;
    __syncthreads();
    for (int d = 128; d > 0; d >>= 1) {
        if (tid < d) s[tid] += s[tid + d];
        __syncthreads();
    }
    if (tid == 0) bsum[blockIdx.x] = s[0];
}

__global__ void k_scanB(const int* __restrict__ bsum, int* __restrict__ bpre, int nb) {
    __shared__ int s[256];
    int tid = threadIdx.x;
    int v = (tid < nb) ? bsum[tid] : 0;
    s[tid] = v;
    __syncthreads();
    for (int d = 1; d < 256; d <<= 1) {
        int t = (tid >= d) ? s[tid - d] : 0;
        __syncthreads();
        s[tid] += t;
        __syncthreads();
    }
    if (tid < nb) bpre[tid] = s[tid] - v;  // exclusive
}

// exclusive per-element offsets + dis = rsqrt(1+deg)
__global__ void k_scanC(const int* __restrict__ cnt, const int* __restrict__ bpre,
                        int* __restrict__ off, float* __restrict__ dis, int n) {
    __shared__ int s[256];
    int tid = threadIdx.x;
    int i = blockIdx.x * 256 + tid;
    int v = (i < n) ? cnt[i] : 0;
    s[tid] = v;
    __syncthreads();
    for (int d = 1; d < 256; d <<= 1) {
        int t = (tid >= d) ? s[tid - d] : 0;
        __syncthreads();
        s[tid] += t;
        __syncthreads();
    }
    if (i < n) {
        off[i] = bpre[blockIdx.x] + s[tid] - v;
        dis[i] = rsqrtf(1.0f + (float)v);
    }
}

// slot = off[row]++ ; csr[slot] = {col, w}. After this, off[i] == segment END.
__global__ void k_fill(const int* __restrict__ row, const int* __restrict__ col,
                       const float* __restrict__ ew, const float* __restrict__ dis,
                       int* __restrict__ off, int2* __restrict__ csr, int ne) {
    int i = blockIdx.x * blockDim.x + threadIdx.x;
    int st = gridDim.x * blockDim.x;
    for (; i < ne; i += st) {
        int r = row[i], c = col[i];
        float w = dis[r] * ew[i] * dis[c];
        int slot = atomicAdd(&off[r], 1);
        csr[slot] = make_int2(c, __float_as_int(w));
    }
}

// ---- dense: Y[nrows,64] = op(X) @ W[64,64]; op = relu(x+bias) if RELU_BIAS --

template <bool RELU_BIAS>
__global__ __launch_bounds__(256) void k_gemm64(const float* __restrict__ X,
                                                const float* __restrict__ W,
                                                const float* __restrict__ bias_in,
                                                float* __restrict__ Y, int nrows) {
    __shared__ float Wl[64 * 64];   // [k][f]
    __shared__ float XT[64 * 68];   // [k][r], padded
    int tid = threadIdx.x;
    int r0 = blockIdx.x * 64;
    for (int i = tid; i < 64 * 64; i += 256) Wl[i] = W[i];
    for (int i = tid; i < 64 * 64; i += 256) {
        int r = i >> 6, k = i & 63;
        int rr = r0 + r;
        float v = 0.f;
        if (rr < nrows) {
            v = X[(size_t)r0 * 64 + i];
            if (RELU_BIAS) v = fmaxf(v + bias_in[k], 0.f);
        }
        XT[k * 68 + r] = v;
    }
    __syncthreads();
    int f4 = (tid & 15) * 4;
    int r4 = (tid >> 4) * 4;
    float acc[4][4];
#pragma unroll
    for (int i = 0; i < 4; ++i)
#pragma unroll
        for (int j = 0; j < 4; ++j) acc[i][j] = 0.f;
#pragma unroll 8
    for (int k = 0; k < 64; ++k) {
        float4 w = *(const float4*)&Wl[k * 64 + f4];
        float4 xv = *(const float4*)&XT[k * 68 + r4];
        float xs[4] = {xv.x, xv.y, xv.z, xv.w};
        float ws[4] = {w.x, w.y, w.z, w.w};
#pragma unroll
        for (int i = 0; i < 4; ++i)
#pragma unroll
            for (int j = 0; j < 4; ++j) acc[i][j] = fmaf(xs[i], ws[j], acc[i][j]);
    }
#pragma unroll
    for (int i = 0; i < 4; ++i) {
        int rr = r0 + r4 + i;
        if (rr < nrows) {
            float4 o = make_float4(acc[i][0], acc[i][1], acc[i][2], acc[i][3]);
            *(float4*)&Y[(size_t)rr * 64 + f4] = o;
        }
    }
}

// ---- pull aggregation: AGG[i] = dis[i]^2*H[i] + sum_in w*H[c] ------------
// wave per node; lanes = (sub-edge 0..3) x (feat-quad 0..15); 4 gathers in flight

__global__ __launch_bounds__(256) void k_agg(const int* __restrict__ off_end,
                                             const int* __restrict__ cnt,
                                             const float* __restrict__ dis,
                                             const int2* __restrict__ csr,
                                             const float* __restrict__ H,
                                             float* __restrict__ AGG, int n) {
    int l = threadIdx.x & 63;
    int node = (blockIdx.x * blockDim.x + threadIdx.x) >> 6;
    if (node >= n) return;
    int sub = l >> 4;
    int q4 = (l & 15) * 4;
    int endv = off_end[node];
    int s = endv - cnt[node];
    float4 acc = make_float4(0.f, 0.f, 0.f, 0.f);
    for (int e = s + sub; e < endv; e += 4) {
        int2 p = csr[e];
        float w = __int_as_float(p.y);
        float4 h = *(const float4*)&H[(size_t)p.x * 64 + q4];
        acc.x = fmaf(w, h.x, acc.x);
        acc.y = fmaf(w, h.y, acc.y);
        acc.z = fmaf(w, h.z, acc.z);
        acc.w = fmaf(w, h.w, acc.w);
    }
#pragma unroll
    for (int m = 16; m <= 32; m <<= 1) {
        acc.x += __shfl_xor(acc.x, m, 64);
        acc.y += __shfl_xor(acc.y, m, 64);
        acc.z += __shfl_xor(acc.z, m, 64);
        acc.w += __shfl_xor(acc.w, m, 64);
    }
    if (sub == 0) {
        float d = dis[node];
        float d2 = d * d;
        float4 hs = *(const float4*)&H[(size_t)node * 64 + q4];
        acc.x = fmaf(d2, hs.x, acc.x);
        acc.y = fmaf(d2, hs.y, acc.y);
        acc.z = fmaf(d2, hs.z, acc.z);
        acc.w = fmaf(d2, hs.w, acc.w);
        *(float4*)&AGG[(size_t)node * 64 + q4] = acc;
    }
}

// ---- fused MLP head: out = relu((AGG+b2)@fc1 + fc1b) @ fc2 + fc2b --------
// 64 rows/block; fc1 in two 64-col halves (16KB W tile); fc2 via register
// partials + shfl_xor reduce over the 16 threads sharing a row. ~40KB LDS.

__global__ __launch_bounds__(256, 4) void k_mlp(const float* __restrict__ AGG,
                                                const float* __restrict__ b2,
                                                const float* __restrict__ fc1w,
                                                const float* __restrict__ fc1b,
                                                const float* __restrict__ fc2w,
                                                const float* __restrict__ fc2b,
                                                float* __restrict__ out, int n) {
    __shared__ float XT[64 * 68];    // [k][r] transposed input tile, 17.4KB
    __shared__ float Wh[64 * 64];    // one 64-col half of fc1w, 16KB
    __shared__ float W2l[128 * 10];  // 5KB
    __shared__ float b1l[128];
    __shared__ float b2c[16];
    int tid = threadIdx.x;
    int r0 = blockIdx.x * 64;
    // stage XT (with conv2 bias), W2, b1, b2, fc1 half 0
    for (int i = tid; i < 64 * 64; i += 256) {
        int r = i >> 6, k = i & 63;
        int rr = r0 + r;
        float v = 0.f;
        if (rr < n) v = AGG[(size_t)r0 * 64 + i] + b2[k];
        XT[k * 68 + r] = v;
    }
    for (int i = tid; i < 64 * 64; i += 256)
        Wh[i] = fc1w[(i >> 6) * 128 + (i & 63)];
    for (int i = tid; i < 128 * 10; i += 256) W2l[i] = fc2w[i];
    if (tid < 128) b1l[tid] = fc1b[tid];
    if (tid < 10) b2c[tid] = fc2b[tid];
    __syncthreads();

    int f4 = (tid & 15) * 4;
    int r4 = (tid >> 4) * 4;
    float pacc[4][10];
#pragma unroll
    for (int i = 0; i < 4; ++i)
#pragma unroll
        for (int c = 0; c < 10; ++c) pacc[i][c] = 0.f;

#pragma unroll
    for (int h = 0; h < 2; ++h) {
        if (h == 1) {
            __syncthreads();  // everyone done reading Wh half 0
            for (int i = tid; i < 64 * 64; i += 256)
                Wh[i] = fc1w[(i >> 6) * 128 + 64 + (i & 63)];
            __syncthreads();
        }
        float acc[4][4];
#pragma unroll
        for (int i = 0; i < 4; ++i)
#pragma unroll
            for (int j = 0; j < 4; ++j) acc[i][j] = 0.f;
#pragma unroll 8
        for (int k = 0; k < 64; ++k) {
            float4 xv = *(const float4*)&XT[k * 68 + r4];
            float4 wv = *(const float4*)&Wh[k * 64 + f4];
            float xs[4] = {xv.x, xv.y, xv.z, xv.w};
            float ws[4] = {wv.x, wv.y, wv.z, wv.w};
#pragma unroll
            for (int i = 0; i < 4; ++i)
#pragma unroll
                for (int j = 0; j < 4; ++j) acc[i][j] = fmaf(xs[i], ws[j], acc[i][j]);
        }
        // relu + bias, then partial fc2 into pacc
#pragma unroll
        for (int jj = 0; jj < 4; ++jj) {
            int jcol = h * 64 + f4 + jj;
            float w2r[10];
#pragma unroll
            for (int c = 0; c < 10; ++c) w2r[c] = W2l[jcol * 10 + c];
            float bj = b1l[jcol];
#pragma unroll
            for (int i = 0; i < 4; ++i) {
                float pv = fmaxf(acc[i][jj] + bj, 0.f);
#pragma unroll
                for (int c = 0; c < 10; ++c) pacc[i][c] = fmaf(pv, w2r[c], pacc[i][c]);
            }
        }
    }
    // reduce pacc over the 16 threads (lanes xor 1,2,4,8) sharing each row
#pragma unroll
    for (int i = 0; i < 4; ++i)
#pragma unroll
        for (int c = 0; c < 10; ++c) {
            float v = pacc[i][c];
            v += __shfl_xor(v, 1, 64);
            v += __shfl_xor(v, 2, 64);
            v += __shfl_xor(v, 4, 64);
            v += __shfl_xor(v, 8, 64);
            pacc[i][c] = v;
        }
    if ((tid & 15) == 0) {
#pragma unroll
        for (int i = 0; i < 4; ++i) {
            int rr = r0 + r4 + i;
            if (rr < n) {
#pragma unroll
                for (int c = 0; c < 10; ++c)
                    out[(size_t)rr * 10 + c] = pacc[i][c] + b2c[c];
            }
        }
    }
}

// --------------------------------------------------------------------------

extern "C" void kernel_launch(void* const* d_in, const int* in_sizes, int n_in,
                              void* d_out, int out_size, void* d_ws, size_t ws_size,
                              hipStream_t stream) {
    const float* x     = (const float*)d_in[0];
    const int*   eidx  = (const int*)d_in[1];
    const float* eattr = (const float*)d_in[2];
    const float* W1    = (const float*)d_in[3];
    const float* b1    = (const float*)d_in[4];
    const float* W2    = (const float*)d_in[5];
    const float* b2    = (const float*)d_in[6];
    const float* fc1w  = (const float*)d_in[7];
    const float* fc1b  = (const float*)d_in[8];
    const float* fc2w  = (const float*)d_in[9];
    const float* fc2b  = (const float*)d_in[10];
    float* out = (float*)d_out;

    const int N = in_sizes[0] / NFEAT;   // 50000
    const int E = in_sizes[2];           // 800000
    const int* row = eidx;
    const int* col = eidx + E;

    // workspace layout
    int*   icnt = (int*)d_ws;                  // N (padded 50176)
    int*   off  = icnt + 50176;                // N
    float* dis  = (float*)(off + 50176);       // N
    int*   bsum = (int*)(dis + 50176);         // 256
    int*   bpre = bsum + 256;                  // 256
    int2*  csr  = (int2*)(bpre + 256);         // E
    float* H    = (float*)(csr + E);           // N*64
    float* AGG  = H + (size_t)N * 64;          // N*64

    const int TB = 256;
    int gN = (N + TB - 1) / TB;                // 196
    int gG = (N + 63) / 64;                    // 782
    int gA = (N * 64 + TB - 1) / TB;           // 12500
    int nb = gN;

    hipMemsetAsync(icnt, 0, (size_t)N * sizeof(int), stream);
    k_hist<<<1024, TB, 0, stream>>>(row, icnt, E);
    k_scanA<<<nb, TB, 0, stream>>>(icnt, bsum, N);
    k_scanB<<<1, TB, 0, stream>>>(bsum, bpre, nb);
    k_scanC<<<nb, TB, 0, stream>>>(icnt, bpre, off, dis, N);
    k_fill<<<1024, TB, 0, stream>>>(row, col, eattr, dis, off, csr, E);

    // layer 1
    k_gemm64<false><<<gG, TB, 0, stream>>>(x, W1, nullptr, H, N);
    k_agg<<<gA, TB, 0, stream>>>(off, icnt, dis, csr, H, AGG, N);
    // layer 2
    k_gemm64<true><<<gG, TB, 0, stream>>>(AGG, W2, b1, H, N);
    k_agg<<<gA, TB, 0, stream>>>(off, icnt, dis, csr, H, AGG, N);
    // MLP head
    k_mlp<<<gG, TB, 0, stream>>>(AGG, b2, fc1w, fc1b, fc2w, fc2b, out, N);
}